// Round 3
// baseline (452.768 us; speedup 1.0000x reference)
//
#include <hip/hip_runtime.h>
#include <hip/hip_bf16.h>
#include <math.h>

typedef short short8 __attribute__((ext_vector_type(8)));
typedef short short4v __attribute__((ext_vector_type(4)));
typedef float f32x4 __attribute__((ext_vector_type(4)));
typedef __bf16 bf16x8 __attribute__((ext_vector_type(8)));

#define DEVI __device__ __forceinline__

DEVI float bf2f(short u) {
  union { unsigned int u32; float f; } c;
  c.u32 = ((unsigned int)(unsigned short)u) << 16;
  return c.f;
}
DEVI short f2bf(float f) {
  __hip_bfloat16 h = __float2bfloat16(f);
  unsigned short u;
  __builtin_memcpy(&u, &h, 2);
  return (short)u;
}
DEVI f32x4 mfma16(bf16x8 a, bf16x8 b, f32x4 c) {
  return __builtin_amdgcn_mfma_f32_16x16x32_bf16(a, b, c, 0, 0, 0);
}

#define GLL16(gsrc, ldst) __builtin_amdgcn_global_load_lds( \
    (__attribute__((address_space(1))) void*)(gsrc), \
    (__attribute__((address_space(3))) void*)(ldst), 16, 0, 0)

// ---------------- prep: x -> bf16 (B,C,L) and transposed (B,L,C) ----------------
__global__ __launch_bounds__(256) void k_prep_x(const float* __restrict__ x,
                                                short* __restrict__ xbf,
                                                short* __restrict__ xT) {
  __shared__ short T[64][66];
  int t = threadIdx.x;
  int lt = blockIdx.x & 127;
  int ct = (blockIdx.x >> 7) & 1;
  int b  = blockIdx.x >> 8;
  int c0 = ct << 6, l0 = lt << 6;
  int i = t >> 2, j4 = (t & 3) << 4;
  const float* src = x + (size_t)(b * 128 + c0 + i) * 8192 + l0 + j4;
  short hv[16];
#pragma unroll
  for (int e = 0; e < 16; e += 4) {
    float4 v = *(const float4*)(src + e);
    hv[e] = f2bf(v.x); hv[e + 1] = f2bf(v.y); hv[e + 2] = f2bf(v.z); hv[e + 3] = f2bf(v.w);
  }
  short8 o0, o1;
#pragma unroll
  for (int e = 0; e < 8; ++e) { o0[e] = hv[e]; o1[e] = hv[8 + e]; }
  short* dst = xbf + (size_t)(b * 128 + c0 + i) * 8192 + l0 + j4;
  *(short8*)dst = o0;
  *(short8*)(dst + 8) = o1;
#pragma unroll
  for (int e = 0; e < 16; ++e) T[i][j4 + e] = hv[e];
  __syncthreads();
  int jj = t >> 2, i4 = (t & 3) << 4;
  short8 p0, p1;
#pragma unroll
  for (int e = 0; e < 8; ++e) { p0[e] = T[i4 + e][jj]; p1[e] = T[i4 + 8 + e][jj]; }
  short* d2 = xT + ((size_t)b * 8192 + l0 + jj) * 128 + c0 + i4;
  *(short8*)d2 = p0;
  *(short8*)(d2 + 8) = p1;
}

// ---------------- prep: forward twiddle table Tf [1024][8192], rows 2m=cos, 2m+1=-sin ----
__global__ __launch_bounds__(256) void k_prep_tf(short* __restrict__ tf) {
  int n = blockIdx.x >> 2;
  int l0 = ((blockIdx.x & 3) << 11) + (threadIdx.x << 3);
  int m = n >> 1;
  int odd = n & 1;
  short8 o;
#pragma unroll
  for (int e = 0; e < 8; ++e) {
    int l = l0 + e;
    int r = (m * l) & 8191;
    float s, c;
    sincospif((float)r * (1.0f / 4096.0f), &s, &c);
    o[e] = f2bf(odd ? -s : c);
  }
  *(short8*)(tf + (size_t)n * 8192 + l0) = o;
}

// ---------------- prep: inverse twiddle Ti [8192][1024], cols k<512 cos, >=512 sin ------
__global__ __launch_bounds__(256) void k_prep_ti(short* __restrict__ ti) {
  int l = blockIdx.x;
  int k0 = threadIdx.x << 2;
  short4v o;
#pragma unroll
  for (int e = 0; e < 4; ++e) {
    int k = k0 + e;
    int m = (k < 512) ? k : (k - 512);
    int r = (m * l) & 8191;
    float s, c;
    sincospif((float)r * (1.0f / 4096.0f), &s, &c);
    o[e] = f2bf((k < 512) ? c : s);
  }
  *(short4v*)(ti + (size_t)l * 1024 + k0) = o;
}

// ---------------- prep: pack weights bf16 ----------------
__global__ __launch_bounds__(256) void k_prep_w(const float* __restrict__ w1,
                                                const float* __restrict__ w2,
                                                const float* __restrict__ w3,
                                                const float* __restrict__ pw_w,
                                                short* __restrict__ w12,
                                                short* __restrict__ w3p,
                                                short* __restrict__ pwb) {
  int idx = blockIdx.x * 256 + threadIdx.x;
  if (idx < 98304) {             // w12 [768][128]: rows 0..351 w1, 384..735 w2, rest 0
    int j = idx >> 7, c = idx & 127;
    float v = 0.f;
    if (j < 352) v = w1[j * 128 + c];
    else if (j >= 384 && j < 736) v = w2[(j - 384) * 128 + c];
    w12[idx] = f2bf(v);
  } else if (idx < 147456) {     // w3p [128][384]
    int q = idx - 98304;
    int o = q / 384, h = q - o * 384;
    w3p[q] = f2bf(h < 352 ? w3[o * 352 + h] : 0.f);
  } else if (idx < 163840) {     // pw_w [128][128]
    int q = idx - 147456;
    pwb[q] = f2bf(pw_w[q]);
  }
}

// ---------------- prep: bias[b][o] = tb+pw_b+dw_b + silu(t_emb) @ tw^T ----------------
__global__ __launch_bounds__(256) void k_prep_bias(const float* __restrict__ t_emb,
                                                   const float* __restrict__ tw,
                                                   const float* __restrict__ tb,
                                                   const float* __restrict__ pw_b,
                                                   const float* __restrict__ dw_b,
                                                   float* __restrict__ bias) {
  __shared__ float s[256];
  int b = blockIdx.x, t = threadIdx.x;
  float v = t_emb[b * 256 + t];
  s[t] = v / (1.0f + __expf(-v));
  __syncthreads();
  if (t < 128) {
    float acc = tb[t] + pw_b[t] + dw_b[t];
    for (int j = 0; j < 256; ++j) acc += s[j] * tw[t * 256 + j];
    bias[b * 128 + t] = acc;
  }
}

__global__ __launch_bounds__(256) void k_zero(float4* __restrict__ p, int n4) {
  int i = blockIdx.x * 256 + threadIdx.x;
  if (i < n4) p[i] = make_float4(0.f, 0.f, 0.f, 0.f);
}

// ---------------- forward partial DFT GEMM: X[1024][1024] += x_bf @ Tf^T, split-K=8 ----
__global__ __launch_bounds__(256, 2) void k_fwd(const short* __restrict__ A,
                                                const short* __restrict__ Bt,
                                                float* __restrict__ X) {
  __shared__ short As[2][4096];
  __shared__ short Bs[2][4096];
  int t = threadIdx.x;
  int nt = blockIdx.x & 7;
  int mt = (blockIdx.x >> 3) & 7;
  int kc = blockIdx.x >> 6;
  int lane = t & 63, wv = t >> 6;
  int wr = wv >> 1, wc = wv & 1;

  int rA = t >> 2, g = t & 3;
  int gs0 = (g ^ ((rA >> 1) & 3)) << 3;
  int rB = rA + 64;
  int gs1 = (g ^ ((rB >> 1) & 3)) << 3;

  const short* aS0 = A + (size_t)(mt * 128 + rA) * 8192 + kc * 1024 + gs0;
  const short* aS1 = A + (size_t)(mt * 128 + rB) * 8192 + kc * 1024 + gs1;
  const short* bS0 = Bt + (size_t)(nt * 128 + rA) * 8192 + kc * 1024 + gs0;
  const short* bS1 = Bt + (size_t)(nt * 128 + rB) * 8192 + kc * 1024 + gs1;

  f32x4 acc[4][4];
#pragma unroll
  for (int i = 0; i < 4; ++i)
#pragma unroll
    for (int j = 0; j < 4; ++j) acc[i][j] = (f32x4){0.f, 0.f, 0.f, 0.f};

  GLL16(aS0, &As[0][t * 8]);
  GLL16(aS1, &As[0][2048 + t * 8]);
  GLL16(bS0, &Bs[0][t * 8]);
  GLL16(bS1, &Bs[0][2048 + t * 8]);

  int rowk = lane & 15, kg = lane >> 4;

  for (int ks = 0; ks < 32; ++ks) {
    __syncthreads();
    int buf = ks & 1;
    if (ks + 1 < 32) {
      int ko = (ks + 1) * 32;
      GLL16(aS0 + ko, &As[buf ^ 1][t * 8]);
      GLL16(aS1 + ko, &As[buf ^ 1][2048 + t * 8]);
      GLL16(bS0 + ko, &Bs[buf ^ 1][t * 8]);
      GLL16(bS1 + ko, &Bs[buf ^ 1][2048 + t * 8]);
    }
    bf16x8 af[4], bfr[4];
#pragma unroll
    for (int fr = 0; fr < 4; ++fr) {
      int rr = wr * 64 + fr * 16 + rowk;
      int gg = kg ^ ((rr >> 1) & 3);
      af[fr] = *(const bf16x8*)(&As[buf][rr * 32 + gg * 8]);
    }
#pragma unroll
    for (int fc = 0; fc < 4; ++fc) {
      int rr = wc * 64 + fc * 16 + rowk;
      int gg = kg ^ ((rr >> 1) & 3);
      bfr[fc] = *(const bf16x8*)(&Bs[buf][rr * 32 + gg * 8]);
    }
#pragma unroll
    for (int fr = 0; fr < 4; ++fr)
#pragma unroll
      for (int fc = 0; fc < 4; ++fc)
        acc[fr][fc] = mfma16(af[fr], bfr[fc], acc[fr][fc]);
  }

  int rbase = mt * 128 + wr * 64 + (lane >> 4) * 4;
  int cbase = nt * 128 + wc * 64 + (lane & 15);
#pragma unroll
  for (int fr = 0; fr < 4; ++fr)
#pragma unroll
    for (int fc = 0; fc < 4; ++fc)
#pragma unroll
      for (int j = 0; j < 4; ++j)
        unsafeAtomicAdd(&X[(size_t)(rbase + fr * 16 + j) * 1024 + cbase + fc * 16],
                        acc[fr][fc][j]);
}

// ---------------- spectral mix: D[(b,o)][k] = scaled(rot*(W^T X) - X) ----------------
__global__ __launch_bounds__(256) void k_spec(const float* __restrict__ X,
                                              const float* __restrict__ wre,
                                              const float* __restrict__ wim,
                                              const float* __restrict__ shifts,
                                              short* __restrict__ D) {
  int t = threadIdx.x;
  int mt = blockIdx.x & 31, ot = blockIdx.x >> 5;
  int m = mt * 16 + (t & 15);
  int o = ot * 16 + (t >> 4);
  float ar[8], ai[8];
#pragma unroll
  for (int b = 0; b < 8; ++b) { ar[b] = 0.f; ai[b] = 0.f; }
  for (int c = 0; c < 128; ++c) {
    float wr = wre[((size_t)c * 128 + o) * 512 + m];
    float wi = wim[((size_t)c * 128 + o) * 512 + m];
#pragma unroll
    for (int b = 0; b < 8; ++b) {
      float2 xv = *(const float2*)(X + ((size_t)(b * 128 + c)) * 1024 + 2 * m);
      ar[b] += xv.x * wr - xv.y * wi;
      ai[b] += xv.x * wi + xv.y * wr;
    }
  }
  float phi = -6.283185307179586f * shifts[o] * (float)m;
  float sp, cp;
  sincosf(phi, &sp, &cp);
  float sc = (m == 0 ? 1.0f : 2.0f) * (1.0f / 8192.0f);
#pragma unroll
  for (int b = 0; b < 8; ++b) {
    float yr = ar[b] * cp - ai[b] * sp;
    float yi = ar[b] * sp + ai[b] * cp;
    float2 xo = *(const float2*)(X + ((size_t)(b * 128 + o)) * 1024 + 2 * m);
    D[((size_t)b * 128 + o) * 1024 + m]       = f2bf(sc * (yr - xo.x));
    D[((size_t)b * 128 + o) * 1024 + 512 + m] = f2bf(-sc * (yi - xo.y));
  }
}

// ---------------- inverse DFT + pointwise + depthwise + bias + x -> h_pre (B,L,C) -----
__global__ __launch_bounds__(256, 2) void k_inv(const short* __restrict__ Ti,
                                                const short* __restrict__ D,
                                                const short* __restrict__ xT,
                                                const short* __restrict__ pwb,
                                                const float* __restrict__ dww,
                                                const float* __restrict__ bias,
                                                short* __restrict__ hp) {
  __shared__ short Sm[16384];   // As[2][4096] | Bs[2][4096]; reused as x tile in epilogue
  __shared__ short xedge[256];
  short* As = Sm;
  short* Bs = Sm + 8192;
  int t = threadIdx.x;
  int lt = blockIdx.x & 63;
  int b  = blockIdx.x >> 6;
  int l0 = lt << 7;
  int lane = t & 63, wv = t >> 6;
  int wr = wv >> 1, wc = wv & 1;

  int rA = t >> 2, g = t & 3;
  int gs0 = (g ^ ((rA >> 1) & 3)) << 3;
  int rB = rA + 64;
  int gs1 = (g ^ ((rB >> 1) & 3)) << 3;

  const short* a1_0 = Ti + (size_t)(l0 + rA) * 1024 + gs0;
  const short* a1_1 = Ti + (size_t)(l0 + rB) * 1024 + gs1;
  const short* b1_0 = D + (size_t)(b * 128 + rA) * 1024 + gs0;
  const short* b1_1 = D + (size_t)(b * 128 + rB) * 1024 + gs1;
  const short* a2_0 = xT + ((size_t)b * 8192 + l0 + rA) * 128 + gs0;
  const short* a2_1 = xT + ((size_t)b * 8192 + l0 + rB) * 128 + gs1;
  const short* b2_0 = pwb + rA * 128 + gs0;
  const short* b2_1 = pwb + rB * 128 + gs1;

  f32x4 acc[4][4];
#pragma unroll
  for (int i = 0; i < 4; ++i)
#pragma unroll
    for (int j = 0; j < 4; ++j) acc[i][j] = (f32x4){0.f, 0.f, 0.f, 0.f};

  auto stage = [&](int buf, int ks) {
    int bo = buf * 4096;
    if (ks < 32) {
      int ko = ks * 32;
      GLL16(a1_0 + ko, &As[bo + t * 8]);
      GLL16(a1_1 + ko, &As[bo + 2048 + t * 8]);
      GLL16(b1_0 + ko, &Bs[bo + t * 8]);
      GLL16(b1_1 + ko, &Bs[bo + 2048 + t * 8]);
    } else {
      int ko = (ks - 32) * 32;
      GLL16(a2_0 + ko, &As[bo + t * 8]);
      GLL16(a2_1 + ko, &As[bo + 2048 + t * 8]);
      GLL16(b2_0 + ko, &Bs[bo + t * 8]);
      GLL16(b2_1 + ko, &Bs[bo + 2048 + t * 8]);
    }
  };

  stage(0, 0);
  int rowk = lane & 15, kg = lane >> 4;
  for (int ks = 0; ks < 36; ++ks) {
    __syncthreads();
    int buf = ks & 1;
    if (ks + 1 < 36) stage(buf ^ 1, ks + 1);
    bf16x8 af[4], bfr[4];
#pragma unroll
    for (int fr = 0; fr < 4; ++fr) {
      int rr = wr * 64 + fr * 16 + rowk;
      int gg = kg ^ ((rr >> 1) & 3);
      af[fr] = *(const bf16x8*)(&As[buf * 4096 + rr * 32 + gg * 8]);
    }
#pragma unroll
    for (int fc = 0; fc < 4; ++fc) {
      int rr = wc * 64 + fc * 16 + rowk;
      int gg = kg ^ ((rr >> 1) & 3);
      bfr[fc] = *(const bf16x8*)(&Bs[buf * 4096 + rr * 32 + gg * 8]);
    }
#pragma unroll
    for (int fr = 0; fr < 4; ++fr)
#pragma unroll
      for (int fc = 0; fc < 4; ++fc)
        acc[fr][fc] = mfma16(af[fr], bfr[fc], acc[fr][fc]);
  }

  // restage x tile (rows l0..l0+127) + edge rows into LDS
  __syncthreads();
  for (int i = t; i < 2080; i += 256) {
    if (i < 2048) {
      int row = i >> 4, seg = i & 15;
      short8 v = *(const short8*)(xT + ((size_t)b * 8192 + l0 + row) * 128 + seg * 8);
      *(short8*)(&Sm[row * 128 + seg * 8]) = v;
    } else {
      int e2 = i - 2048;
      int which = e2 >> 4, seg = e2 & 15;
      int l = which ? (l0 + 128) : (l0 - 1);
      short8 v = {0, 0, 0, 0, 0, 0, 0, 0};
      if (l >= 0 && l < 8192)
        v = *(const short8*)(xT + ((size_t)b * 8192 + l) * 128 + seg * 8);
      *(short8*)(&xedge[which * 128 + seg * 8]) = v;
    }
  }
  __syncthreads();

  const float* bb = bias + b * 128;
#pragma unroll
  for (int fc = 0; fc < 4; ++fc) {
    int o = wc * 64 + fc * 16 + rowk;
    float w0 = dww[o * 3], w1v = dww[o * 3 + 1], w2v = dww[o * 3 + 2];
    float bo = bb[o];
#pragma unroll
    for (int fr = 0; fr < 4; ++fr) {
#pragma unroll
      for (int j = 0; j < 4; ++j) {
        int ll = wr * 64 + fr * 16 + kg * 4 + j;
        float xm = (ll == 0)   ? bf2f(xedge[o])       : bf2f(Sm[(ll - 1) * 128 + o]);
        float x0 = bf2f(Sm[ll * 128 + o]);
        float xp = (ll == 127) ? bf2f(xedge[128 + o]) : bf2f(Sm[(ll + 1) * 128 + o]);
        float v = acc[fr][fc][j] + w0 * xm + w1v * x0 + w2v * xp + bo + x0;
        hp[((size_t)b * 8192 + l0 + ll) * 128 + o] = f2bf(v);
      }
    }
  }
}

// ---------------- RMSNorm + SwiGLU + residual -> out (B,C,L) f32 ----------------
__global__ __launch_bounds__(512, 2) void k_swi(const short* __restrict__ hp,
                                                const short* __restrict__ w12,
                                                const short* __restrict__ w3p,
                                                const float* __restrict__ normw,
                                                const float* __restrict__ x,
                                                float* __restrict__ out) {
  __shared__ short smem[32768];   // 64KB: hA [64][128] | uA [64][384]; reused as tr f32[128][65]
  short* hA = smem;
  short* uA = smem + 8192;
  float* tr = (float*)smem;

  int t = threadIdx.x;
  int rb = blockIdx.x;
  int bb_ = rb >> 7;
  int l0 = (rb & 127) << 6;
  size_t row0 = (size_t)rb * 64;

  {
    int row = t >> 3, j = t & 7;
    const short* src = hp + (row0 + row) * 128 + j * 16;
    short8 v0 = *(const short8*)src;
    short8 v1 = *(const short8*)(src + 8);
    float f[16];
#pragma unroll
    for (int e = 0; e < 8; ++e) { f[e] = bf2f(v0[e]); f[8 + e] = bf2f(v1[e]); }
    float ss = 0.f;
#pragma unroll
    for (int e = 0; e < 16; ++e) ss += f[e] * f[e];
    ss += __shfl_xor(ss, 1);
    ss += __shfl_xor(ss, 2);
    ss += __shfl_xor(ss, 4);
    float rms = rsqrtf(ss * (1.0f / 128.0f) + 1e-6f);
    int cb = j * 16;
    short8 o0, o1;
#pragma unroll
    for (int e = 0; e < 8; ++e) {
      o0[e] = f2bf(f[e] * rms * normw[cb + e]);
      o1[e] = f2bf(f[8 + e] * rms * normw[cb + 8 + e]);
    }
    int g0 = (j * 2) ^ (row & 7);
    int g1 = (j * 2 + 1) ^ (row & 7);
    *(short8*)(&hA[row * 128 + g0 * 8]) = o0;
    *(short8*)(&hA[row * 128 + g1 * 8]) = o1;
  }
  __syncthreads();

  int lane = t & 63, wv = t >> 6;
  int wr = wv >> 2, wq = wv & 3;
  int rowk = lane & 15, kg = lane >> 4;

  f32x4 acc1[2][6], acc2[2][6];
#pragma unroll
  for (int i = 0; i < 2; ++i)
#pragma unroll
    for (int j = 0; j < 6; ++j) {
      acc1[i][j] = (f32x4){0.f, 0.f, 0.f, 0.f};
      acc2[i][j] = (f32x4){0.f, 0.f, 0.f, 0.f};
    }
#pragma unroll
  for (int ks = 0; ks < 4; ++ks) {
    bf16x8 a[2];
#pragma unroll
    for (int fr = 0; fr < 2; ++fr) {
      int rr = wr * 32 + fr * 16 + rowk;
      int gg = (ks * 4 + kg) ^ (rr & 7);
      a[fr] = *(const bf16x8*)(&hA[rr * 128 + gg * 8]);
    }
    int kk = ks * 32 + kg * 8;
#pragma unroll
    for (int fc = 0; fc < 6; ++fc) {
      int n = wq * 96 + fc * 16 + rowk;
      bf16x8 b1 = *(const bf16x8*)(w12 + (size_t)n * 128 + kk);
      bf16x8 b2 = *(const bf16x8*)(w12 + (size_t)(n + 384) * 128 + kk);
#pragma unroll
      for (int fr = 0; fr < 2; ++fr) {
        acc1[fr][fc] = mfma16(a[fr], b1, acc1[fr][fc]);
        acc2[fr][fc] = mfma16(a[fr], b2, acc2[fr][fc]);
      }
    }
  }
#pragma unroll
  for (int fr = 0; fr < 2; ++fr)
#pragma unroll
    for (int fc = 0; fc < 6; ++fc)
#pragma unroll
      for (int j = 0; j < 4; ++j) {
        float a1 = acc1[fr][fc][j], a2 = acc2[fr][fc][j];
        float u = a1 / (1.f + __expf(-a1)) * a2;
        int row = wr * 32 + fr * 16 + kg * 4 + j;
        int col = wq * 96 + fc * 16 + rowk;
        int cg = (col >> 3) ^ (row & 7);
        uA[row * 384 + cg * 8 + (col & 7)] = f2bf(u);
      }
  __syncthreads();

  f32x4 acc[2][2];
#pragma unroll
  for (int i = 0; i < 2; ++i)
#pragma unroll
    for (int j = 0; j < 2; ++j) acc[i][j] = (f32x4){0.f, 0.f, 0.f, 0.f};
#pragma unroll
  for (int ks = 0; ks < 12; ++ks) {
    bf16x8 a[2];
#pragma unroll
    for (int fr = 0; fr < 2; ++fr) {
      int rr = wr * 32 + fr * 16 + rowk;
      int gg = (ks * 4 + kg) ^ (rr & 7);
      a[fr] = *(const bf16x8*)(&uA[rr * 384 + gg * 8]);
    }
    int kk = ks * 32 + kg * 8;
#pragma unroll
    for (int fc = 0; fc < 2; ++fc) {
      int n = wq * 32 + fc * 16 + rowk;
      bf16x8 bw = *(const bf16x8*)(w3p + (size_t)n * 384 + kk);
#pragma unroll
      for (int fr = 0; fr < 2; ++fr) acc[fr][fc] = mfma16(a[fr], bw, acc[fr][fc]);
    }
  }
  __syncthreads();   // done with hA/uA -> reuse as tr
#pragma unroll
  for (int fr = 0; fr < 2; ++fr)
#pragma unroll
    for (int fc = 0; fc < 2; ++fc)
#pragma unroll
      for (int j = 0; j < 4; ++j) {
        int r = wr * 32 + fr * 16 + kg * 4 + j;
        int c = wq * 32 + fc * 16 + rowk;
        tr[c * 65 + r] = acc[fr][fc][j];
      }
  __syncthreads();
  {
    int o = t >> 2, q = t & 3;
    const float* xs = x + ((size_t)(bb_ * 128 + o)) * 8192 + l0 + q * 16;
    float* os = out + ((size_t)(bb_ * 128 + o)) * 8192 + l0 + q * 16;
#pragma unroll
    for (int e4 = 0; e4 < 4; ++e4) {
      float4 xv = *(const float4*)(xs + e4 * 4);
      float4 r;
      r.x = tr[o * 65 + q * 16 + e4 * 4 + 0] + xv.x;
      r.y = tr[o * 65 + q * 16 + e4 * 4 + 1] + xv.y;
      r.z = tr[o * 65 + q * 16 + e4 * 4 + 2] + xv.z;
      r.w = tr[o * 65 + q * 16 + e4 * 4 + 3] + xv.w;
      *(float4*)(os + e4 * 4) = r;
    }
  }
}

// ---------------- launch ----------------
extern "C" void kernel_launch(void* const* d_in, const int* in_sizes, int n_in,
                              void* d_out, int out_size, void* d_ws, size_t ws_size,
                              hipStream_t stream) {
  const float* x      = (const float*)d_in[0];
  const float* t_emb  = (const float*)d_in[1];
  const float* w_real = (const float*)d_in[2];
  const float* w_imag = (const float*)d_in[3];
  const float* shifts = (const float*)d_in[4];
  const float* pw_w   = (const float*)d_in[5];
  const float* pw_b   = (const float*)d_in[6];
  const float* dw_w   = (const float*)d_in[7];
  const float* dw_b   = (const float*)d_in[8];
  const float* norm_w = (const float*)d_in[9];
  const float* w1     = (const float*)d_in[10];
  const float* w2     = (const float*)d_in[11];
  const float* w3     = (const float*)d_in[12];
  const float* tw     = (const float*)d_in[13];
  const float* tb     = (const float*)d_in[14];
  float* out = (float*)d_out;
  char* ws = (char*)d_ws;

  short* xbf  = (short*)(ws + 0);              // 16.78 MB
  short* xT   = (short*)(ws + 16777216);       // 16.78 MB
  short* tf   = (short*)(ws + 33554432);       // 16.78 MB
  short* ti   = (short*)(ws + 50331648);       // 16.78 MB
  float* Xb   = (float*)(ws + 67108864);       // 4.19 MB
  short* Db   = (short*)(ws + 71303168);       // 2.10 MB
  short* hpre = (short*)(ws + 73400320);       // 16.78 MB
  short* w12  = (short*)(ws + 90177536);       // 196 KB
  short* w3p  = (short*)(ws + 90374144);       // 98 KB
  short* pwb  = (short*)(ws + 90472448);       // 32 KB
  float* bias = (float*)(ws + 90505216);       // 4 KB

  k_prep_x<<<2048, 256, 0, stream>>>(x, xbf, xT);
  k_prep_tf<<<4096, 256, 0, stream>>>(tf);
  k_prep_ti<<<8192, 256, 0, stream>>>(ti);
  k_prep_w<<<640, 256, 0, stream>>>(w1, w2, w3, pw_w, w12, w3p, pwb);
  k_prep_bias<<<8, 256, 0, stream>>>(t_emb, tw, tb, pw_b, dw_b, bias);
  k_zero<<<1024, 256, 0, stream>>>((float4*)Xb, 262144);
  k_fwd<<<512, 256, 0, stream>>>(xbf, tf, Xb);
  k_spec<<<256, 256, 0, stream>>>(Xb, w_real, w_imag, shifts, Db);
  k_inv<<<512, 256, 0, stream>>>(ti, Db, xT, pwb, dw_w, bias, hpre);
  k_swi<<<1024, 512, 0, stream>>>(hpre, w12, w3p, norm_w, x, out);
}

// Round 7
// 404.786 us; speedup vs baseline: 1.1185x; 1.1185x over previous
//
#include <hip/hip_runtime.h>
#include <hip/hip_bf16.h>
#include <math.h>

typedef short short8 __attribute__((ext_vector_type(8)));
typedef short short4v __attribute__((ext_vector_type(4)));
typedef float f32x4 __attribute__((ext_vector_type(4)));
typedef __bf16 bf16x8 __attribute__((ext_vector_type(8)));

#define DEVI __device__ __forceinline__

DEVI float bf2f(short u) {
  union { unsigned int u32; float f; } c;
  c.u32 = ((unsigned int)(unsigned short)u) << 16;
  return c.f;
}
DEVI short f2bf(float f) {
  __hip_bfloat16 h = __float2bfloat16(f);
  unsigned short u;
  __builtin_memcpy(&u, &h, 2);
  return (short)u;
}
DEVI f32x4 mfma16(bf16x8 a, bf16x8 b, f32x4 c) {
  return __builtin_amdgcn_mfma_f32_16x16x32_bf16(a, b, c, 0, 0, 0);
}

#define GLL16(gsrc, ldst) __builtin_amdgcn_global_load_lds( \
    (__attribute__((address_space(1))) void*)(gsrc), \
    (__attribute__((address_space(3))) void*)(ldst), 16, 0, 0)

// ---------------- prep: x -> bf16 (B,C,L) and transposed (B,L,C) ----------------
__global__ __launch_bounds__(256) void k_prep_x(const float* __restrict__ x,
                                                short* __restrict__ xbf,
                                                short* __restrict__ xT) {
  __shared__ short T[64][66];
  int t = threadIdx.x;
  int lt = blockIdx.x & 127;
  int ct = (blockIdx.x >> 7) & 1;
  int b  = blockIdx.x >> 8;
  int c0 = ct << 6, l0 = lt << 6;
  int i = t >> 2, j4 = (t & 3) << 4;
  const float* src = x + (size_t)(b * 128 + c0 + i) * 8192 + l0 + j4;
  short hv[16];
#pragma unroll
  for (int e = 0; e < 16; e += 4) {
    float4 v = *(const float4*)(src + e);
    hv[e] = f2bf(v.x); hv[e + 1] = f2bf(v.y); hv[e + 2] = f2bf(v.z); hv[e + 3] = f2bf(v.w);
  }
  short8 o0, o1;
#pragma unroll
  for (int e = 0; e < 8; ++e) { o0[e] = hv[e]; o1[e] = hv[8 + e]; }
  short* dst = xbf + (size_t)(b * 128 + c0 + i) * 8192 + l0 + j4;
  *(short8*)dst = o0;
  *(short8*)(dst + 8) = o1;
#pragma unroll
  for (int e = 0; e < 16; ++e) T[i][j4 + e] = hv[e];
  __syncthreads();
  int jj = t >> 2, i4 = (t & 3) << 4;
  short8 p0, p1;
#pragma unroll
  for (int e = 0; e < 8; ++e) { p0[e] = T[i4 + e][jj]; p1[e] = T[i4 + 8 + e][jj]; }
  short* d2 = xT + ((size_t)b * 8192 + l0 + jj) * 128 + c0 + i4;
  *(short8*)d2 = p0;
  *(short8*)(d2 + 8) = p1;
}

// ---------------- prep: forward twiddle table Tf [1024][8192], rows 2m=cos, 2m+1=-sin ----
__global__ __launch_bounds__(256) void k_prep_tf(short* __restrict__ tf) {
  int n = blockIdx.x >> 2;
  int l0 = ((blockIdx.x & 3) << 11) + (threadIdx.x << 3);
  int m = n >> 1;
  int odd = n & 1;
  short8 o;
#pragma unroll
  for (int e = 0; e < 8; ++e) {
    int l = l0 + e;
    int r = (m * l) & 8191;
    float s, c;
    sincospif((float)r * (1.0f / 4096.0f), &s, &c);
    o[e] = f2bf(odd ? -s : c);
  }
  *(short8*)(tf + (size_t)n * 8192 + l0) = o;
}

// ---------------- prep: inverse twiddle Ti [8192][1024], cols k<512 cos, >=512 sin ------
__global__ __launch_bounds__(256) void k_prep_ti(short* __restrict__ ti) {
  int l = blockIdx.x;
  int k0 = threadIdx.x << 2;
  short4v o;
#pragma unroll
  for (int e = 0; e < 4; ++e) {
    int k = k0 + e;
    int m = (k < 512) ? k : (k - 512);
    int r = (m * l) & 8191;
    float s, c;
    sincospif((float)r * (1.0f / 4096.0f), &s, &c);
    o[e] = f2bf((k < 512) ? c : s);
  }
  *(short4v*)(ti + (size_t)l * 1024 + k0) = o;
}

// ---------------- prep: pack weights bf16, FRAGMENT-MAJOR for coalesced wave loads ----
// w12f: 48 n-tiles(16) x 4 ks x 64 lanes x 8 elems  (w1 rows 0..351 -> nt 0..23 ; w2 -> nt 24..47)
// w3f :  8 n-tiles(16) x 12 ks x 64 lanes x 8 elems
__global__ __launch_bounds__(256) void k_prep_w(const float* __restrict__ w1,
                                                const float* __restrict__ w2,
                                                const float* __restrict__ w3,
                                                const float* __restrict__ pw_w,
                                                short* __restrict__ w12f,
                                                short* __restrict__ w3f,
                                                short* __restrict__ pwb) {
  int idx = blockIdx.x * 256 + threadIdx.x;
  if (idx < 98304) {
    int e = idx & 7, lane = (idx >> 3) & 63, ks = (idx >> 9) & 3, nt = idx >> 11;
    int rowk = lane & 15, kg = lane >> 4;
    int n = nt * 16 + rowk;          // 0..767
    int k = ks * 32 + kg * 8 + e;    // 0..127
    float v = 0.f;
    if (n < 352) v = w1[n * 128 + k];
    else if (n >= 384 && n < 736) v = w2[(n - 384) * 128 + k];
    w12f[idx] = f2bf(v);
  } else if (idx < 147456) {
    int q = idx - 98304;             // 0..49151
    int e = q & 7, lane = (q >> 3) & 63;
    int rest = q >> 9;               // 0..95
    int nt = rest / 12, ks = rest - nt * 12;
    int rowk = lane & 15, kg = lane >> 4;
    int n = nt * 16 + rowk;          // 0..127
    int k = ks * 32 + kg * 8 + e;    // 0..383
    w3f[q] = f2bf(k < 352 ? w3[n * 352 + k] : 0.f);
  } else if (idx < 163840) {
    int q = idx - 147456;
    pwb[q] = f2bf(pw_w[q]);
  }
}

// ---------------- prep: bias[b][o] = tb+pw_b+dw_b + silu(t_emb) @ tw^T ----------------
__global__ __launch_bounds__(256) void k_prep_bias(const float* __restrict__ t_emb,
                                                   const float* __restrict__ tw,
                                                   const float* __restrict__ tb,
                                                   const float* __restrict__ pw_b,
                                                   const float* __restrict__ dw_b,
                                                   float* __restrict__ bias) {
  __shared__ float s[256];
  int b = blockIdx.x, t = threadIdx.x;
  float v = t_emb[b * 256 + t];
  s[t] = v / (1.0f + __expf(-v));
  __syncthreads();
  if (t < 128) {
    float acc = tb[t] + pw_b[t] + dw_b[t];
    for (int j = 0; j < 256; ++j) acc += s[j] * tw[t * 256 + j];
    bias[b * 128 + t] = acc;
  }
}

__global__ __launch_bounds__(256) void k_zero(float4* __restrict__ p, int n4) {
  int i = blockIdx.x * 256 + threadIdx.x;
  if (i < n4) p[i] = make_float4(0.f, 0.f, 0.f, 0.f);
}

// ---------------- forward partial DFT GEMM: X[1024][1024] += x_bf @ Tf^T, split-K=8 ----
__global__ __launch_bounds__(256, 2) void k_fwd(const short* __restrict__ A,
                                                const short* __restrict__ Bt,
                                                float* __restrict__ X) {
  __shared__ short As[2][4096];
  __shared__ short Bs[2][4096];
  int t = threadIdx.x;
  int nt = blockIdx.x & 7;
  int mt = (blockIdx.x >> 3) & 7;
  int kc = blockIdx.x >> 6;
  int lane = t & 63, wv = t >> 6;
  int wr = wv >> 1, wc = wv & 1;

  int rA = t >> 2, g = t & 3;
  int gs0 = (g ^ ((rA >> 1) & 3)) << 3;
  int rB = rA + 64;
  int gs1 = (g ^ ((rB >> 1) & 3)) << 3;

  const short* aS0 = A + (size_t)(mt * 128 + rA) * 8192 + kc * 1024 + gs0;
  const short* aS1 = A + (size_t)(mt * 128 + rB) * 8192 + kc * 1024 + gs1;
  const short* bS0 = Bt + (size_t)(nt * 128 + rA) * 8192 + kc * 1024 + gs0;
  const short* bS1 = Bt + (size_t)(nt * 128 + rB) * 8192 + kc * 1024 + gs1;

  f32x4 acc[4][4];
#pragma unroll
  for (int i = 0; i < 4; ++i)
#pragma unroll
    for (int j = 0; j < 4; ++j) acc[i][j] = (f32x4){0.f, 0.f, 0.f, 0.f};

  GLL16(aS0, &As[0][t * 8]);
  GLL16(aS1, &As[0][2048 + t * 8]);
  GLL16(bS0, &Bs[0][t * 8]);
  GLL16(bS1, &Bs[0][2048 + t * 8]);

  int rowk = lane & 15, kg = lane >> 4;

  for (int ks = 0; ks < 32; ++ks) {
    __syncthreads();
    int buf = ks & 1;
    if (ks + 1 < 32) {
      int ko = (ks + 1) * 32;
      GLL16(aS0 + ko, &As[buf ^ 1][t * 8]);
      GLL16(aS1 + ko, &As[buf ^ 1][2048 + t * 8]);
      GLL16(bS0 + ko, &Bs[buf ^ 1][t * 8]);
      GLL16(bS1 + ko, &Bs[buf ^ 1][2048 + t * 8]);
    }
    bf16x8 af[4], bfr[4];
#pragma unroll
    for (int fr = 0; fr < 4; ++fr) {
      int rr = wr * 64 + fr * 16 + rowk;
      int gg = kg ^ ((rr >> 1) & 3);
      af[fr] = *(const bf16x8*)(&As[buf][rr * 32 + gg * 8]);
    }
#pragma unroll
    for (int fc = 0; fc < 4; ++fc) {
      int rr = wc * 64 + fc * 16 + rowk;
      int gg = kg ^ ((rr >> 1) & 3);
      bfr[fc] = *(const bf16x8*)(&Bs[buf][rr * 32 + gg * 8]);
    }
#pragma unroll
    for (int fr = 0; fr < 4; ++fr)
#pragma unroll
      for (int fc = 0; fc < 4; ++fc)
        acc[fr][fc] = mfma16(af[fr], bfr[fc], acc[fr][fc]);
  }

  int rbase = mt * 128 + wr * 64 + (lane >> 4) * 4;
  int cbase = nt * 128 + wc * 64 + (lane & 15);
#pragma unroll
  for (int fr = 0; fr < 4; ++fr)
#pragma unroll
    for (int fc = 0; fc < 4; ++fc)
#pragma unroll
      for (int j = 0; j < 4; ++j)
        unsafeAtomicAdd(&X[(size_t)(rbase + fr * 16 + j) * 1024 + cbase + fc * 16],
                        acc[fr][fc][j]);
}

// ---------------- spectral mix: D[(b,o)][k] = scaled(rot*(W^T X) - X) ----------------
// 512 threads: 256 (m,o) pairs x 2 c-halves; LDS combine. unroll-4 for load ILP.
__global__ __launch_bounds__(512) void k_spec(const float* __restrict__ X,
                                              const float* __restrict__ wre,
                                              const float* __restrict__ wim,
                                              const float* __restrict__ shifts,
                                              short* __restrict__ D) {
  __shared__ float red[16][256];
  int t = threadIdx.x;
  int tt = t & 255;
  int ch = t >> 8;
  int mt = blockIdx.x & 31, ot = blockIdx.x >> 5;
  int m = mt * 16 + (tt & 15);
  int o = ot * 16 + (tt >> 4);
  float ar[8], ai[8];
#pragma unroll
  for (int b = 0; b < 8; ++b) { ar[b] = 0.f; ai[b] = 0.f; }
  int cb = ch * 64;
  const float* wrp = wre + (size_t)(cb * 128 + o) * 512 + m;
  const float* wip = wim + (size_t)(cb * 128 + o) * 512 + m;
  const float* Xp = X + 2 * m;
#pragma unroll 4
  for (int cc = 0; cc < 64; ++cc) {
    float wr = wrp[(size_t)cc * 65536];
    float wi = wip[(size_t)cc * 65536];
    int c = cb + cc;
#pragma unroll
    for (int b = 0; b < 8; ++b) {
      float2 xv = *(const float2*)(Xp + (size_t)(b * 128 + c) * 1024);
      ar[b] += xv.x * wr - xv.y * wi;
      ai[b] += xv.x * wi + xv.y * wr;
    }
  }
  if (ch) {
#pragma unroll
    for (int b = 0; b < 8; ++b) { red[b * 2][tt] = ar[b]; red[b * 2 + 1][tt] = ai[b]; }
  }
  __syncthreads();
  if (!ch) {
#pragma unroll
    for (int b = 0; b < 8; ++b) { ar[b] += red[b * 2][tt]; ai[b] += red[b * 2 + 1][tt]; }
    float phi = -6.283185307179586f * shifts[o] * (float)m;
    float sp, cp;
    sincosf(phi, &sp, &cp);
    float sc = (m == 0 ? 1.0f : 2.0f) * (1.0f / 8192.0f);
#pragma unroll
    for (int b = 0; b < 8; ++b) {
      float yr = ar[b] * cp - ai[b] * sp;
      float yi = ar[b] * sp + ai[b] * cp;
      float2 xo = *(const float2*)(X + (size_t)(b * 128 + o) * 1024 + 2 * m);
      D[((size_t)b * 128 + o) * 1024 + m]       = f2bf(sc * (yr - xo.x));
      D[((size_t)b * 128 + o) * 1024 + 512 + m] = f2bf(-sc * (yi - xo.y));
    }
  }
}

// -------- inverse DFT + pointwise + depthwise + bias + x + RMSNorm*norm_w -> hn (B,L,C) ----
__global__ __launch_bounds__(256, 2) void k_inv(const short* __restrict__ Ti,
                                                const short* __restrict__ D,
                                                const short* __restrict__ xT,
                                                const short* __restrict__ pwb,
                                                const float* __restrict__ dww,
                                                const float* __restrict__ bias,
                                                const float* __restrict__ nw,
                                                short* __restrict__ hn) {
  __shared__ short Sm[16384];   // As[2][4096] | Bs[2][4096]; reused as x tile in epilogue
  __shared__ short xedge[256];
  __shared__ float rsS[2][128];
  short* As = Sm;
  short* Bs = Sm + 8192;
  int t = threadIdx.x;
  int lt = blockIdx.x & 63;
  int b  = blockIdx.x >> 6;
  int l0 = lt << 7;
  int lane = t & 63, wv = t >> 6;
  int wr = wv >> 1, wc = wv & 1;

  int rA = t >> 2, g = t & 3;
  int gs0 = (g ^ ((rA >> 1) & 3)) << 3;
  int rB = rA + 64;
  int gs1 = (g ^ ((rB >> 1) & 3)) << 3;

  const short* a1_0 = Ti + (size_t)(l0 + rA) * 1024 + gs0;
  const short* a1_1 = Ti + (size_t)(l0 + rB) * 1024 + gs1;
  const short* b1_0 = D + (size_t)(b * 128 + rA) * 1024 + gs0;
  const short* b1_1 = D + (size_t)(b * 128 + rB) * 1024 + gs1;
  const short* a2_0 = xT + ((size_t)b * 8192 + l0 + rA) * 128 + gs0;
  const short* a2_1 = xT + ((size_t)b * 8192 + l0 + rB) * 128 + gs1;
  const short* b2_0 = pwb + rA * 128 + gs0;
  const short* b2_1 = pwb + rB * 128 + gs1;

  f32x4 acc[4][4];
#pragma unroll
  for (int i = 0; i < 4; ++i)
#pragma unroll
    for (int j = 0; j < 4; ++j) acc[i][j] = (f32x4){0.f, 0.f, 0.f, 0.f};

  auto stage = [&](int buf, int ks) {
    int bo = buf * 4096;
    if (ks < 32) {
      int ko = ks * 32;
      GLL16(a1_0 + ko, &As[bo + t * 8]);
      GLL16(a1_1 + ko, &As[bo + 2048 + t * 8]);
      GLL16(b1_0 + ko, &Bs[bo + t * 8]);
      GLL16(b1_1 + ko, &Bs[bo + 2048 + t * 8]);
    } else {
      int ko = (ks - 32) * 32;
      GLL16(a2_0 + ko, &As[bo + t * 8]);
      GLL16(a2_1 + ko, &As[bo + 2048 + t * 8]);
      GLL16(b2_0 + ko, &Bs[bo + t * 8]);
      GLL16(b2_1 + ko, &Bs[bo + 2048 + t * 8]);
    }
  };

  stage(0, 0);
  int rowk = lane & 15, kg = lane >> 4;
  for (int ks = 0; ks < 36; ++ks) {
    __syncthreads();
    int buf = ks & 1;
    if (ks + 1 < 36) stage(buf ^ 1, ks + 1);
    bf16x8 af[4], bfr[4];
#pragma unroll
    for (int fr = 0; fr < 4; ++fr) {
      int rr = wr * 64 + fr * 16 + rowk;
      int gg = kg ^ ((rr >> 1) & 3);
      af[fr] = *(const bf16x8*)(&As[buf * 4096 + rr * 32 + gg * 8]);
    }
#pragma unroll
    for (int fc = 0; fc < 4; ++fc) {
      int rr = wc * 64 + fc * 16 + rowk;
      int gg = kg ^ ((rr >> 1) & 3);
      bfr[fc] = *(const bf16x8*)(&Bs[buf * 4096 + rr * 32 + gg * 8]);
    }
#pragma unroll
    for (int fr = 0; fr < 4; ++fr)
#pragma unroll
      for (int fc = 0; fc < 4; ++fc)
        acc[fr][fc] = mfma16(af[fr], bfr[fc], acc[fr][fc]);
  }

  // restage x tile (rows l0..l0+127) + edge rows into LDS
  __syncthreads();
  for (int i = t; i < 2080; i += 256) {
    if (i < 2048) {
      int row = i >> 4, seg = i & 15;
      short8 v = *(const short8*)(xT + ((size_t)b * 8192 + l0 + row) * 128 + seg * 8);
      *(short8*)(&Sm[row * 128 + seg * 8]) = v;
    } else {
      int e2 = i - 2048;
      int which = e2 >> 4, seg = e2 & 15;
      int l = which ? (l0 + 128) : (l0 - 1);
      short8 v = {0, 0, 0, 0, 0, 0, 0, 0};
      if (l >= 0 && l < 8192)
        v = *(const short8*)(xT + ((size_t)b * 8192 + l) * 128 + seg * 8);
      *(short8*)(&xedge[which * 128 + seg * 8]) = v;
    }
  }
  __syncthreads();

  // pass 1: finalize h = irfft(D) + pw + dw + bias + x (f32, in acc)
  const float* bb = bias + b * 128;
#pragma unroll
  for (int fc = 0; fc < 4; ++fc) {
    int o = wc * 64 + fc * 16 + rowk;
    float w0 = dww[o * 3], w1v = dww[o * 3 + 1], w2v = dww[o * 3 + 2];
    float bo = bb[o];
#pragma unroll
    for (int fr = 0; fr < 4; ++fr) {
#pragma unroll
      for (int j = 0; j < 4; ++j) {
        int ll = wr * 64 + fr * 16 + kg * 4 + j;
        float xm = (ll == 0)   ? bf2f(xedge[o])       : bf2f(Sm[(ll - 1) * 128 + o]);
        float x0 = bf2f(Sm[ll * 128 + o]);
        float xp = (ll == 127) ? bf2f(xedge[128 + o]) : bf2f(Sm[(ll + 1) * 128 + o]);
        acc[fr][fc][j] += w0 * xm + w1v * x0 + w2v * xp + bo + x0;
      }
    }
  }
  // pass 2: RMS row sums (reduce over fc in-thread, rowk lanes via shfl, wc via LDS)
#pragma unroll
  for (int fr = 0; fr < 4; ++fr) {
#pragma unroll
    for (int j = 0; j < 4; ++j) {
      float s = 0.f;
#pragma unroll
      for (int fc = 0; fc < 4; ++fc) { float v = acc[fr][fc][j]; s += v * v; }
      s += __shfl_xor(s, 1);
      s += __shfl_xor(s, 2);
      s += __shfl_xor(s, 4);
      s += __shfl_xor(s, 8);
      if (rowk == 0) rsS[wc][wr * 64 + fr * 16 + kg * 4 + j] = s;
    }
  }
  __syncthreads();
  // pass 3: normalize * norm_w -> hn bf16
#pragma unroll
  for (int fr = 0; fr < 4; ++fr) {
#pragma unroll
    for (int j = 0; j < 4; ++j) {
      int ll = wr * 64 + fr * 16 + kg * 4 + j;
      float rms = rsqrtf((rsS[0][ll] + rsS[1][ll]) * (1.0f / 128.0f) + 1e-6f);
#pragma unroll
      for (int fc = 0; fc < 4; ++fc) {
        int o = wc * 64 + fc * 16 + rowk;
        hn[((size_t)b * 8192 + l0 + ll) * 128 + o] = f2bf(acc[fr][fc][j] * rms * nw[o]);
      }
    }
  }
}

// ---------------- SwiGLU + residual -> out (B,C,L) f32 (input hn prenormalized) -------
__global__ __launch_bounds__(512, 2) void k_swi(const short* __restrict__ hn,
                                                const short* __restrict__ w12f,
                                                const short* __restrict__ w3f,
                                                const float* __restrict__ x,
                                                float* __restrict__ out) {
  __shared__ short smem[32768];   // 64KB: hA [64][128] | uA [64][384]; reused as tr f32[128][65]
  short* hA = smem;
  short* uA = smem + 8192;
  float* tr = (float*)smem;

  int t = threadIdx.x;
  int lane = t & 63, wv = t >> 6;
  int rb = blockIdx.x;
  int bb_ = rb >> 7;
  int l0 = (rb & 127) << 6;
  size_t row0 = (size_t)rb * 64;

  // stage hn (64x128) -> hA with col-group swizzle: hA[row][g*8+e] = hn[row][(g^(row&7))*8+e]
#pragma unroll
  for (int c = 0; c < 2; ++c) {
    int sidx = (wv * 2 + c) * 512 + lane * 8;
    int row = sidx >> 7;
    int g = (sidx >> 3) & 15;
    const short* src = hn + (row0 + row) * 128 + (g ^ (row & 7)) * 8;
    GLL16(src, &hA[sidx]);
  }
  __syncthreads();

  int wr = wv >> 2, wq = wv & 3;
  int rowk = lane & 15, kg = lane >> 4;

  f32x4 acc1[2][6], acc2[2][6];
#pragma unroll
  for (int i = 0; i < 2; ++i)
#pragma unroll
    for (int j = 0; j < 6; ++j) {
      acc1[i][j] = (f32x4){0.f, 0.f, 0.f, 0.f};
      acc2[i][j] = (f32x4){0.f, 0.f, 0.f, 0.f};
    }
#pragma unroll
  for (int ks = 0; ks < 4; ++ks) {
    bf16x8 a[2];
#pragma unroll
    for (int fr = 0; fr < 2; ++fr) {
      int rr = wr * 32 + fr * 16 + rowk;
      int gg = (ks * 4 + kg) ^ (rr & 7);
      a[fr] = *(const bf16x8*)(&hA[rr * 128 + gg * 8]);
    }
#pragma unroll
    for (int fc = 0; fc < 6; ++fc) {
      int nt = wq * 6 + fc;
      bf16x8 b1 = *(const bf16x8*)(w12f + ((size_t)(nt * 4 + ks) * 64 + lane) * 8);
      bf16x8 b2 = *(const bf16x8*)(w12f + ((size_t)((nt + 24) * 4 + ks) * 64 + lane) * 8);
#pragma unroll
      for (int fr = 0; fr < 2; ++fr) {
        acc1[fr][fc] = mfma16(a[fr], b1, acc1[fr][fc]);
        acc2[fr][fc] = mfma16(a[fr], b2, acc2[fr][fc]);
      }
    }
  }
#pragma unroll
  for (int fr = 0; fr < 2; ++fr)
#pragma unroll
    for (int fc = 0; fc < 6; ++fc)
#pragma unroll
      for (int j = 0; j < 4; ++j) {
        float a1 = acc1[fr][fc][j], a2 = acc2[fr][fc][j];
        float u = a1 / (1.f + __expf(-a1)) * a2;
        int row = wr * 32 + fr * 16 + kg * 4 + j;
        int col = wq * 96 + fc * 16 + rowk;
        int cg = (col >> 3) ^ (row & 7);
        uA[row * 384 + cg * 8 + (col & 7)] = f2bf(u);
      }
  __syncthreads();

  f32x4 acc[2][2];
#pragma unroll
  for (int i = 0; i < 2; ++i)
#pragma unroll
    for (int j = 0; j < 2; ++j) acc[i][j] = (f32x4){0.f, 0.f, 0.f, 0.f};
#pragma unroll
  for (int ks = 0; ks < 12; ++ks) {
    bf16x8 a[2];
#pragma unroll
    for (int fr = 0; fr < 2; ++fr) {
      int rr = wr * 32 + fr * 16 + rowk;
      int gg = (ks * 4 + kg) ^ (rr & 7);
      a[fr] = *(const bf16x8*)(&uA[rr * 384 + gg * 8]);
    }
#pragma unroll
    for (int fc = 0; fc < 2; ++fc) {
      int nt = wq * 2 + fc;
      bf16x8 bw = *(const bf16x8*)(w3f + ((size_t)(nt * 12 + ks) * 64 + lane) * 8);
#pragma unroll
      for (int fr = 0; fr < 2; ++fr) acc[fr][fc] = mfma16(a[fr], bw, acc[fr][fc]);
    }
  }
  __syncthreads();   // done with hA/uA -> reuse as tr
#pragma unroll
  for (int fr = 0; fr < 2; ++fr)
#pragma unroll
    for (int fc = 0; fc < 2; ++fc)
#pragma unroll
      for (int j = 0; j < 4; ++j) {
        int r = wr * 32 + fr * 16 + kg * 4 + j;
        int c = wq * 32 + fc * 16 + rowk;
        tr[c * 65 + r] = acc[fr][fc][j];
      }
  __syncthreads();
  {
    int o = t >> 2, q = t & 3;
    const float* xs = x + ((size_t)(bb_ * 128 + o)) * 8192 + l0 + q * 16;
    float* os = out + ((size_t)(bb_ * 128 + o)) * 8192 + l0 + q * 16;
#pragma unroll
    for (int e4 = 0; e4 < 4; ++e4) {
      float4 xv = *(const float4*)(xs + e4 * 4);
      float4 r;
      r.x = tr[o * 65 + q * 16 + e4 * 4 + 0] + xv.x;
      r.y = tr[o * 65 + q * 16 + e4 * 4 + 1] + xv.y;
      r.z = tr[o * 65 + q * 16 + e4 * 4 + 2] + xv.z;
      r.w = tr[o * 65 + q * 16 + e4 * 4 + 3] + xv.w;
      *(float4*)(os + e4 * 4) = r;
    }
  }
}

// ---------------- launch ----------------
extern "C" void kernel_launch(void* const* d_in, const int* in_sizes, int n_in,
                              void* d_out, int out_size, void* d_ws, size_t ws_size,
                              hipStream_t stream) {
  const float* x      = (const float*)d_in[0];
  const float* t_emb  = (const float*)d_in[1];
  const float* w_real = (const float*)d_in[2];
  const float* w_imag = (const float*)d_in[3];
  const float* shifts = (const float*)d_in[4];
  const float* pw_w   = (const float*)d_in[5];
  const float* pw_b   = (const float*)d_in[6];
  const float* dw_w   = (const float*)d_in[7];
  const float* dw_b   = (const float*)d_in[8];
  const float* norm_w = (const float*)d_in[9];
  const float* w1     = (const float*)d_in[10];
  const float* w2     = (const float*)d_in[11];
  const float* w3     = (const float*)d_in[12];
  const float* tw     = (const float*)d_in[13];
  const float* tb     = (const float*)d_in[14];
  float* out = (float*)d_out;
  char* ws = (char*)d_ws;

  short* xbf  = (short*)(ws + 0);              // 16.78 MB
  short* xT   = (short*)(ws + 16777216);       // 16.78 MB
  short* tf   = (short*)(ws + 33554432);       // 16.78 MB
  short* ti   = (short*)(ws + 50331648);       // 16.78 MB
  float* Xb   = (float*)(ws + 67108864);       // 4.19 MB
  short* Db   = (short*)(ws + 71303168);       // 2.10 MB
  short* hn   = (short*)(ws + 73400320);       // 16.78 MB
  short* w12f = (short*)(ws + 90177536);       // 196 KB
  short* w3f  = (short*)(ws + 90374144);       // 98 KB
  short* pwb  = (short*)(ws + 90472448);       // 32 KB
  float* bias = (float*)(ws + 90505216);       // 4 KB

  k_prep_x<<<2048, 256, 0, stream>>>(x, xbf, xT);
  k_prep_tf<<<4096, 256, 0, stream>>>(tf);
  k_prep_ti<<<8192, 256, 0, stream>>>(ti);
  k_prep_w<<<640, 256, 0, stream>>>(w1, w2, w3, pw_w, w12f, w3f, pwb);
  k_prep_bias<<<8, 256, 0, stream>>>(t_emb, tw, tb, pw_b, dw_b, bias);
  k_zero<<<1024, 256, 0, stream>>>((float4*)Xb, 262144);
  k_fwd<<<512, 256, 0, stream>>>(xbf, tf, Xb);
  k_spec<<<256, 512, 0, stream>>>(Xb, w_real, w_imag, shifts, Db);
  k_inv<<<512, 256, 0, stream>>>(ti, Db, xT, pwb, dw_w, bias, norm_w, hn);
  k_swi<<<1024, 512, 0, stream>>>(hn, w12f, w3f, x, out);
}